// Round 7
// baseline (218.860 us; speedup 1.0000x reference)
//
#include <hip/hip_runtime.h>

// VQ quantizer, fp32: z [131072,64], e [2048,64].
// d_out (flat f32): z_q [131072*64] | indices [131072] (floats) | loss [1].
//
// 2-split bf16 MFMA scan (hh, hl, lh products), argmax of s = dot - esq/2.
//
// R10 (kept): LDS-staged B tiles via global_load_lds(16B), pre-swizzled
// global layout; staging lane*16-linear; fragment reads 2-way alias (free).
// R11/R12/R13 (refuted): fewer __syncthreads / more waves / deferred argmax
// all flat at ~131us, MfmaUtil 33-35% == the documented m97-structure
// plateau: __syncthreads emits s_waitcnt vmcnt(0) lgkmcnt(0) (full drain)
// before s_barrier, stalling every wave on the in-flight global_load_lds
// every iteration.
//
// R14 = T3/T4 port: NO __syncthreads in the K-loop. 4-buffer LDS ring,
// stage-ahead=2, per iter: STAGE(t+2) -> asm s_waitcnt vmcnt(2) (counted,
// never 0: tiles t+1,t+2 stay in flight) -> raw s_barrier -> ds_read ->
// MFMA (T5 setprio(1) wrapped) -> argmax. Each wave's vmcnt(2) retires its
// own tile-t quarter BEFORE the barrier; barrier composes per-wave
// guarantees into tile-complete block-wide (m201 pattern). 4-slot ring +
// 1 barrier/iter bounds skew to 1 iter; writer slot (t+2)&3 never aliases
// a live reader slot. A-fragment global loads precede the first stages so
// their compiler waits don't drain the pipeline.
// Geometry: RF=4 (64 rows/wave), 512 blocks, 2 blocks/CU, 2 waves/SIMD.
// A-fragments PINNED one-time via empty asm ("+v") (anti-remat).
//
// Top-2 gap < EPS_S flags rows into a global list; exact f64 re-solve.
// T=0 => z_out = z_q = e[best].

#define N_ROWS 131072
#define ZD 64
#define KCODES 2048
#define RF 4                 // 16-row fragments per wave (64 rows/wave)
#define EPS_S 2e-3f          // s-scale gap; realistic split error ~2e-5
#define FLAG_CAP 32768

using bf16x8  = __attribute__((ext_vector_type(8))) short;
using floatx4 = __attribute__((ext_vector_type(4))) float;

__device__ inline float bf2f(unsigned short u) {
    union { unsigned int i; float f; } c; c.i = ((unsigned int)u) << 16; return c.f;
}
__device__ inline unsigned short f2bf(float x) {
    union { float f; unsigned int i; } c; c.f = x;
    unsigned int b = c.i + 0x7FFFu + ((c.i >> 16) & 1u);
    return (unsigned short)(b >> 16);
}

// ws byte layout:
//       0: loss f32 | 4: flag count u32
//    4096: esn f32[2048]   (= -esq/2, summed in f64)
//   16384: esq64 f64[2048]
//   32768: etiles, 128 tiles x 4096B; tile = hi[kb][code][8] | lo[kb][code][8]
//          (u16; kb = dim>>3, code = c&15, j = dim&7)   ends 557056
//  557056: eT f32[64*2048]
// 1081344: flags u32[32768]   (ends 1212416)

__global__ void prep_kernel(const float* __restrict__ e, float* __restrict__ ws) {
    int t = threadIdx.x, lane = t & 63, w = t >> 6;
    if (blockIdx.x == 0 && t == 0) { ws[0] = 0.0f; ((unsigned int*)ws)[1] = 0u; }
    int c = blockIdx.x * 4 + w;                   // 512 blocks x 4 waves = 2048
    float* esn = ws + 1024;
    double* esq64 = (double*)((char*)ws + 16384);
    unsigned short* et = (unsigned short*)((char*)ws + 32768);
    float* eT = (float*)((char*)ws + 557056);

    float x = e[(size_t)c * ZD + lane];           // lane = dim k, coalesced
    unsigned short h = f2bf(x);
    unsigned short l = f2bf(x - bf2f(h));
    // swizzled tile layout: tile=c>>4 (2048 u16 stride), hi at +0, lo at +1024
    size_t base = ((size_t)(c >> 4) << 11) + ((lane >> 3) << 7) + ((c & 15) << 3) + (lane & 7);
    et[base]        = h;
    et[base + 1024] = l;
    eT[lane * KCODES + c] = x;
    double s = (double)x * (double)x;
    for (int off = 1; off < 64; off <<= 1) s += __shfl_xor(s, off, 64);
    if (lane == 0) { esq64[c] = s; esn[c] = (float)(-0.5 * s); }
}

// 24 MFMAs (setprio(1)-wrapped) + same-tile argmax for one 16-code tile.
// Two independent 3-chains per rf (a1: en-init, a2: 0-init), summed.
// Top-2 invariant mval >= mv2: new mv2 = median(s, mval_old, mv2).
#define COMPUTE(H0, H1, L0, L1, EN, FCOL) do {                               \
    floatx4 _ai = {EN, EN, EN, EN};                                          \
    floatx4 _zi = {0.0f, 0.0f, 0.0f, 0.0f};                                  \
    floatx4 _p1[RF], _p2[RF];                                                \
    __builtin_amdgcn_s_setprio(1);                                           \
    _Pragma("unroll")                                                        \
    for (int _rf = 0; _rf < RF; _rf++) {                                     \
        floatx4 a1 = _ai;                                                    \
        floatx4 a2 = _zi;                                                    \
        a1 = __builtin_amdgcn_mfma_f32_16x16x32_bf16(Ah[_rf][0], H0, a1, 0, 0, 0); \
        a2 = __builtin_amdgcn_mfma_f32_16x16x32_bf16(Ah[_rf][1], H1, a2, 0, 0, 0); \
        a1 = __builtin_amdgcn_mfma_f32_16x16x32_bf16(Ah[_rf][0], L0, a1, 0, 0, 0); \
        a2 = __builtin_amdgcn_mfma_f32_16x16x32_bf16(Ah[_rf][1], L1, a2, 0, 0, 0); \
        a1 = __builtin_amdgcn_mfma_f32_16x16x32_bf16(Al[_rf][0], H0, a1, 0, 0, 0); \
        a2 = __builtin_amdgcn_mfma_f32_16x16x32_bf16(Al[_rf][1], H1, a2, 0, 0, 0); \
        _p1[_rf] = a1; _p2[_rf] = a2;                                        \
    }                                                                        \
    __builtin_amdgcn_s_setprio(0);                                           \
    _Pragma("unroll")                                                        \
    for (int _rf = 0; _rf < RF; _rf++) {                                     \
        _Pragma("unroll")                                                    \
        for (int _r = 0; _r < 4; _r++) {                                     \
            float _s  = _p1[_rf][_r] + _p2[_rf][_r];                         \
            bool  _gt = _s > mval[_rf][_r];                                  \
            mv2[_rf][_r]  = __builtin_amdgcn_fmed3f(_s, mval[_rf][_r], mv2[_rf][_r]); \
            midx[_rf][_r] = _gt ? (FCOL) : midx[_rf][_r];                    \
            mval[_rf][_r] = fmaxf(_s, mval[_rf][_r]);                        \
        }                                                                    \
    }                                                                        \
} while (0)

// Stage one 4KB tile into ring slot BUF: 256 threads x 16B, lane*16-linear.
// LDS dest base is wave-uniform (w<<10); lane offset (lane*16) is implicit.
#define STAGE(BUF, TILE) do {                                                \
    const char* _src = etiles + ((size_t)((TILE) & 127) << 12)               \
                       + ((size_t)threadIdx.x << 4);                         \
    __builtin_amdgcn_global_load_lds(                                        \
        (const __attribute__((address_space(1))) unsigned int*)_src,         \
        (__attribute__((address_space(3))) unsigned int*)&tilebuf[BUF][w << 10], \
        16, 0, 0);                                                           \
} while (0)

#define READT(BUF, H0, H1, L0, L1) do {                                      \
    H0 = *(const bf16x8*)(const void*)(tilebuf[BUF] + (lane << 4));          \
    H1 = *(const bf16x8*)(const void*)(tilebuf[BUF] + 1024 + (lane << 4));   \
    L0 = *(const bf16x8*)(const void*)(tilebuf[BUF] + 2048 + (lane << 4));   \
    L1 = *(const bf16x8*)(const void*)(tilebuf[BUF] + 3072 + (lane << 4));   \
} while (0)

// T4 iteration: stage t+2, counted vmcnt (own tile-t quarter retired, t+1
// and t+2 stay IN FLIGHT), raw barrier (composes per-wave guarantees),
// ds_read + MFMA + argmax. No full drain anywhere in the loop.
#define ITER_V(CT) do {                                                      \
    STAGE(((CT) + 2) & 3, (CT) + 2);                                         \
    asm volatile("s_waitcnt vmcnt(2)" ::: "memory");                         \
    __builtin_amdgcn_s_barrier();                                            \
    float _en = esn_sm[(CT) * 16 + lrow];                                    \
    bf16x8 h0, h1, l0, l1;                                                   \
    READT((CT) & 3, h0, h1, l0, l1);                                         \
    COMPUTE(h0, h1, l0, l1, _en, fcol);                                      \
    fcol += 16.0f;                                                           \
} while (0)

__global__ __launch_bounds__(256, 2) void vq_mfma(
        const float* __restrict__ z, const float* __restrict__ e,
        float* __restrict__ ws, float* __restrict__ out) {
    const char* etiles = (const char*)ws + 32768;
    unsigned int* cntp  = (unsigned int*)ws + 1;
    unsigned int* flags = (unsigned int*)((char*)ws + 1081344);

    __shared__ __attribute__((aligned(16))) char tilebuf[4][4096];
    __shared__ __attribute__((aligned(16))) float esn_sm[KCODES];

    int lane = threadIdx.x & 63;
    int w    = threadIdx.x >> 6;
    int wid  = blockIdx.x * 4 + w;                // 0..2047
    int row0 = wid * (RF * 16);                   // 64 rows per wave
    int lrow = lane & 15;
    int lq   = lane >> 4;

    // A-fragment build FIRST: its global loads are compiler-waited (results
    // feed f2bf), so issuing them before the stages keeps those waits from
    // draining the staging pipeline.
    bf16x8 Ah[RF][2], Al[RF][2];
#pragma unroll
    for (int rf = 0; rf < RF; rf++)
#pragma unroll
        for (int kc = 0; kc < 2; kc++) {
            const float* zp = z + (size_t)(row0 + rf * 16 + lrow) * ZD + kc * 32 + lq * 8;
            float xv[8];
            *(float4*)(void*)&xv[0] = *(const float4*)(const void*)zp;
            *(float4*)(void*)&xv[4] = *(const float4*)(const void*)(zp + 4);
            bf16x8 h, l;
#pragma unroll
            for (int j = 0; j < 8; j++) {
                unsigned short hb = f2bf(xv[j]);
                h[j] = (short)hb;
                l[j] = (short)f2bf(xv[j] - bf2f(hb));
            }
            Ah[rf][kc] = h; Al[rf][kc] = l;
            // Pin (ONE-TIME, outside loop): asm defs cannot be rematerialized
            // -> fragments stay register-resident across the 128-iter loop.
            asm volatile("" : "+v"(Ah[rf][kc]), "+v"(Al[rf][kc]));
        }

    // Staging prologue: esn (8KB, 2 calls) + tiles 0,1 (stage-ahead=2).
    {
        const char* esrc = (const char*)ws + 4096 + ((size_t)threadIdx.x << 4);
        __builtin_amdgcn_global_load_lds(
            (const __attribute__((address_space(1))) unsigned int*)esrc,
            (__attribute__((address_space(3))) unsigned int*)((char*)esn_sm + (w << 10)),
            16, 0, 0);
        __builtin_amdgcn_global_load_lds(
            (const __attribute__((address_space(1))) unsigned int*)(esrc + 4096),
            (__attribute__((address_space(3))) unsigned int*)((char*)esn_sm + 4096 + (w << 10)),
            16, 0, 0);
    }
    STAGE(0, 0);
    STAGE(1, 1);
    // Outstanding/wave here: esn x2 + tile0 + tile1 = 4. Iter 0 adds tile2
    // (=5) then vmcnt(2) retires esn+tile0 before the first barrier.

    // argmax state on s = dot - esq/2  (argmin d2 == argmax s)
    floatx4 mval[RF], mv2[RF], midx[RF];
#pragma unroll
    for (int rf = 0; rf < RF; rf++)
#pragma unroll
        for (int r = 0; r < 4; r++) {
            mval[rf][r] = -3.0e38f; mv2[rf][r] = -3.0e38f; midx[rf][r] = 0.0f;
        }

    float fcol = (float)lrow;                     // maintained: +16 per tile

    for (int ct = 0; ct < 128; ct += 4) {         // ring slot (CT&3) static
        ITER_V(ct);
        ITER_V(ct + 1);
        ITER_V(ct + 2);
        ITER_V(ct + 3);
    }

    float lacc = 0.0f;
#pragma unroll
    for (int rf = 0; rf < RF; rf++)
#pragma unroll
        for (int r = 0; r < 4; r++) {
            float v = mval[rf][r], v2 = mv2[rf][r], fi = midx[rf][r];
            // top-2 max-merge across the 16 lanes of this row (ties: smaller col)
            for (int off = 1; off < 16; off <<= 1) {
                float ov  = __shfl_xor(v,  off, 64);
                float ofi = __shfl_xor(fi, off, 64);
                float ov2 = __shfl_xor(v2, off, 64);
                bool take = (ov > v) || ((ov == v) && (ofi < fi));
                float loser = take ? v : ov;
                v2 = fmaxf(fmaxf(v2, ov2), loser);
                v  = take ? ov  : v;
                fi = take ? ofi : fi;
            }
            int row = row0 + rf * 16 + lq * 4 + r;
            int idx = (int)fi;
            float4 ev = ((const float4*)(const void*)(e + (size_t)idx * ZD))[lrow];
            float4 zv = ((const float4*)(const void*)(z + (size_t)row * ZD))[lrow];
            ((float4*)(void*)(out + (size_t)row * ZD))[lrow] = ev;
            float dx = ev.x - zv.x, dy = ev.y - zv.y;
            float dz = ev.z - zv.z, dw = ev.w - zv.w;
            lacc = fmaf(dx, dx, lacc); lacc = fmaf(dy, dy, lacc);
            lacc = fmaf(dz, dz, lacc); lacc = fmaf(dw, dw, lacc);
            if (lrow == 0) {
                out[(size_t)N_ROWS * ZD + row] = fi;
                if (v - v2 < EPS_S) {
                    unsigned int i = atomicAdd(cntp, 1u);
                    if (i < FLAG_CAP) flags[i] = (unsigned int)row;
                }
            }
        }

    for (int off = 1; off < 64; off <<= 1) lacc += __shfl_xor(lacc, off, 64);
    __shared__ float sm[4];
    if (lane == 0) sm[w] = lacc;
    __syncthreads();
    if (threadIdx.x == 0) atomicAdd(ws, sm[0] + sm[1] + sm[2] + sm[3]);
}

__global__ __launch_bounds__(256) void vq_fixup(
        const float* __restrict__ z, const float* __restrict__ e,
        float* __restrict__ ws, float* __restrict__ out) {
    const double* esq64 = (const double*)((const char*)ws + 16384);
    const float* eT = (const float*)((const char*)ws + 557056);
    const unsigned int* flags = (const unsigned int*)((const char*)ws + 1081344);
    unsigned int cnt = ((const unsigned int*)ws)[1];
    if (cnt > FLAG_CAP) cnt = FLAG_CAP;

    // finalize folded in: stream-ordered after vq_mfma, ws[0] is final.
    if (blockIdx.x == 0 && threadIdx.x == 0)
        out[(size_t)N_ROWS * ZD + N_ROWS] = ws[0] * (1.0f / 8388608.0f);

    __shared__ float zrow[ZD];
    __shared__ double sd[4]; __shared__ int si[4]; __shared__ int sbest;
    int t = threadIdx.x, lane = t & 63, w = t >> 6;

    for (unsigned int u = blockIdx.x; u < cnt; u += gridDim.x) {
        int row = (int)flags[u];
        __syncthreads();                          // protect zrow from prev iter
        if (t < ZD) zrow[t] = z[(size_t)row * ZD + t];
        __syncthreads();

        double dacc[8];
#pragma unroll
        for (int j = 0; j < 8; j++) dacc[j] = 0.0;
        for (int k = 0; k < ZD; k++) {
            double zk = (double)zrow[k];
            const float* ek = eT + k * KCODES + t;
#pragma unroll
            for (int j = 0; j < 8; j++)
                dacc[j] = fma(zk, (double)ek[256 * j], dacc[j]);
        }
        double dmin = 1.0e300; int imin = 0;
#pragma unroll
        for (int j = 0; j < 8; j++) {             // ascending c: first wins
            int c = t + 256 * j;
            double d = fma(-2.0, dacc[j], esq64[c]);
            if (d < dmin) { dmin = d; imin = c; }
        }
        for (int off = 1; off < 64; off <<= 1) {
            double od = __shfl_xor(dmin, off, 64);
            int    oi = __shfl_xor(imin, off, 64);
            if (od < dmin || (od == dmin && oi < imin)) { dmin = od; imin = oi; }
        }
        if (lane == 0) { sd[w] = dmin; si[w] = imin; }
        __syncthreads();
        if (t == 0) {
            double bd = sd[0]; int bi = si[0];
            for (int q = 1; q < 4; q++)
                if (sd[q] < bd || (sd[q] == bd && si[q] < bi)) { bd = sd[q]; bi = si[q]; }
            sbest = bi;
        }
        __syncthreads();
        int bi = sbest;
        if (t < 16)
            ((float4*)(void*)(out + (size_t)row * ZD))[t] =
                ((const float4*)(const void*)(e + (size_t)bi * ZD))[t];
        if (t == 0) out[(size_t)N_ROWS * ZD + row] = (float)bi;
        // loss correction from flips: < EPS * ~700 / 8.4M < 2e-7 — ignored.
    }
}

extern "C" void kernel_launch(void* const* d_in, const int* in_sizes, int n_in,
                              void* d_out, int out_size, void* d_ws, size_t ws_size,
                              hipStream_t stream) {
    const float* z = (const float*)d_in[0];
    const float* e = (const float*)d_in[1];
    float* out = (float*)d_out;
    float* ws  = (float*)d_ws;

    prep_kernel<<<dim3(512), dim3(256), 0, stream>>>(e, ws);
    vq_mfma<<<dim3(512), dim3(256), 0, stream>>>(z, e, ws, out);
    vq_fixup<<<dim3(256), dim3(256), 0, stream>>>(z, e, ws, out);
}

// Round 8
// 203.343 us; speedup vs baseline: 1.0763x; 1.0763x over previous
//
#include <hip/hip_runtime.h>

// VQ quantizer, fp32: z [131072,64], e [2048,64].
// d_out (flat f32): z_q [131072*64] | indices [131072] (floats) | loss [1].
//
// R15: SINGLE-PRODUCT F16 MFMA scan (was 3-product bf16 2-split).
// Rationale: R10-R14 proved schedule-invariance (131+-3us, MfmaUtil 33+-2
// across fewer-barriers / more-waves / deferred-argmax / counted-vmcnt) ->
// per-SIMD time is the SUM of MFMA + VALU + fixed idle; only totals matter.
// f16 dot error std ~3.2e-3; EPS_S=0.03 (6.6 sigma of pairwise error) ->
// flip-miss P ~1e-5 overall; expected flags ~10-12K, exact-f64 fixup at
// 1024 blocks handles them (~12us). Loss drift from pass-A flips ~2e-7
// relative (ignored, same argument as the old EPS comment).
// Per 16-code tile per wave: 8 MFMAs (was 24), B-tile 2KB (was 4KB; two
// tiles staged per 4KB slab, 64 barriers), A-frags 32 VGPR (was 64).
// Structure otherwise = proven R10: global_load_lds(16B) pre-swizzled
// tiles, double-buffered LDS, __syncthreads pipeline; esn in LDS.
// A-fragments PINNED one-time via empty asm ("+v") (anti-remat).
// Flags live in the freed lo-tile region: CAP 65536 + overflow fallback
// (scan all rows) = slow-but-correct in the impossible tail.

#define N_ROWS 131072
#define ZD 64
#define KCODES 2048
#define RF 4                 // 16-row fragments per wave (64 rows/wave)
#define EPS_S 0.03f          // 6.6 sigma of f16 scan pairwise error
#define FLAG_CAP 65536

using f16x8   = __attribute__((ext_vector_type(8))) _Float16;
using floatx4 = __attribute__((ext_vector_type(4))) float;

// ws byte layout:
//       0: loss f32 | 4: flag count u32
//    4096: esn f32[2048]   (= -esq/2, summed in f64)
//   16384: esq64 f64[2048]
//   32768: et16, 128 tiles x 2048B; tile = [kb 0..7][code 0..15][8 k] f16
//          (kb = dim>>3, j = dim&7)   ends 294912
//  294912: flags u32[65536]   (ends 557056)
//  557056: eT f32[64*2048]    (ends 1081344)

__global__ void prep_kernel(const float* __restrict__ e, float* __restrict__ ws) {
    int t = threadIdx.x, lane = t & 63, w = t >> 6;
    if (blockIdx.x == 0 && t == 0) { ws[0] = 0.0f; ((unsigned int*)ws)[1] = 0u; }
    int c = blockIdx.x * 4 + w;                   // 512 blocks x 4 waves = 2048
    float* esn = ws + 1024;
    double* esq64 = (double*)((char*)ws + 16384);
    unsigned short* et = (unsigned short*)((char*)ws + 32768);
    float* eT = (float*)((char*)ws + 557056);

    float x = e[(size_t)c * ZD + lane];           // lane = dim k, coalesced
    union { _Float16 h; unsigned short u; } cv;
    cv.h = (_Float16)x;                           // RTN f32->f16
    // swizzled tile layout: tile = c>>4, 1024 u16 per tile
    int base = ((c >> 4) << 10) + ((lane >> 3) << 7) + ((c & 15) << 3) + (lane & 7);
    et[base] = cv.u;
    eT[lane * KCODES + c] = x;
    double s = (double)x * (double)x;
    for (int off = 1; off < 64; off <<= 1) s += __shfl_xor(s, off, 64);
    if (lane == 0) { esq64[c] = s; esn[c] = (float)(-0.5 * s); }
}

// 8 MFMAs + argmax update for one 16-code tile (single f16 product).
// Top-2 invariant mval >= mv2: new mv2 = median(s, mval_old, mv2).
#define COMPUTE(H0, H1, EN, FCOL) do {                                       \
    floatx4 _ai = {EN, EN, EN, EN};                                          \
    _Pragma("unroll")                                                        \
    for (int _rf = 0; _rf < RF; _rf++) {                                     \
        floatx4 acc;                                                         \
        acc = __builtin_amdgcn_mfma_f32_16x16x32_f16(Fh[_rf][0], H0, _ai, 0, 0, 0); \
        acc = __builtin_amdgcn_mfma_f32_16x16x32_f16(Fh[_rf][1], H1, acc, 0, 0, 0); \
        _Pragma("unroll")                                                    \
        for (int _r = 0; _r < 4; _r++) {                                     \
            float _s  = acc[_r];                                             \
            bool  _gt = _s > mval[_rf][_r];                                  \
            mv2[_rf][_r]  = __builtin_amdgcn_fmed3f(_s, mval[_rf][_r], mv2[_rf][_r]); \
            midx[_rf][_r] = _gt ? (FCOL) : midx[_rf][_r];                    \
            mval[_rf][_r] = fmaxf(_s, mval[_rf][_r]);                        \
        }                                                                    \
    }                                                                        \
} while (0)

// Stage one 4KB PAIR of tiles (2x 2KB) into slab BUF: 256 thr x 16B, linear.
#define STAGEP(BUF, P) do {                                                  \
    const char* _src = etiles + ((size_t)((P) & 63) << 12)                   \
                       + ((size_t)threadIdx.x << 4);                         \
    __builtin_amdgcn_global_load_lds(                                        \
        (const __attribute__((address_space(1))) unsigned int*)_src,         \
        (__attribute__((address_space(3))) unsigned int*)&tilebuf[BUF][w << 10], \
        16, 0, 0);                                                           \
} while (0)

// One pipeline step over a tile PAIR: stage pair P+1, compute tiles 2P,2P+1.
#define ITER2(BUF, P) do {                                                   \
    STAGEP((BUF) ^ 1, (P) + 1);                                              \
    float _en0 = esn_sm[(P) * 32 + lrow];                                    \
    float _en1 = esn_sm[(P) * 32 + 16 + lrow];                               \
    f16x8 h0, h1;                                                            \
    h0 = *(const f16x8*)(const void*)(tilebuf[BUF] + (lane << 4));           \
    h1 = *(const f16x8*)(const void*)(tilebuf[BUF] + 1024 + (lane << 4));    \
    COMPUTE(h0, h1, _en0, fcol);                                             \
    fcol += 16.0f;                                                           \
    h0 = *(const f16x8*)(const void*)(tilebuf[BUF] + 2048 + (lane << 4));    \
    h1 = *(const f16x8*)(const void*)(tilebuf[BUF] + 3072 + (lane << 4));    \
    COMPUTE(h0, h1, _en1, fcol);                                             \
    fcol += 16.0f;                                                           \
    __syncthreads();                                                         \
} while (0)

__global__ __launch_bounds__(256, 2) void vq_mfma(
        const float* __restrict__ z, const float* __restrict__ e,
        float* __restrict__ ws, float* __restrict__ out) {
    const char* etiles = (const char*)ws + 32768;
    unsigned int* cntp  = (unsigned int*)ws + 1;
    unsigned int* flags = (unsigned int*)((char*)ws + 294912);

    __shared__ __attribute__((aligned(16))) char tilebuf[2][4096];
    __shared__ __attribute__((aligned(16))) float esn_sm[KCODES];

    int lane = threadIdx.x & 63;
    int w    = threadIdx.x >> 6;
    int wid  = blockIdx.x * 4 + w;                // 0..2047
    int row0 = wid * (RF * 16);                   // 64 rows per wave
    int lrow = lane & 15;
    int lq   = lane >> 4;

    // Resident A fragments (f16), A[m=lane&15][k=lq*8+j], kc = k-half
    f16x8 Fh[RF][2];
#pragma unroll
    for (int rf = 0; rf < RF; rf++)
#pragma unroll
        for (int kc = 0; kc < 2; kc++) {
            const float* zp = z + (size_t)(row0 + rf * 16 + lrow) * ZD + kc * 32 + lq * 8;
            float xv[8];
            *(float4*)(void*)&xv[0] = *(const float4*)(const void*)zp;
            *(float4*)(void*)&xv[4] = *(const float4*)(const void*)(zp + 4);
            f16x8 h;
#pragma unroll
            for (int j = 0; j < 8; j++) h[j] = (_Float16)xv[j];
            Fh[rf][kc] = h;
            // Pin (ONE-TIME, outside loop): asm defs cannot be rematerialized
            // -> fragments stay register-resident across the loop.
            asm volatile("" : "+v"(Fh[rf][kc]));
        }

    // Prologue staging: esn (8KB, 2 calls) + pair 0.
    {
        const char* esrc = (const char*)ws + 4096 + ((size_t)threadIdx.x << 4);
        __builtin_amdgcn_global_load_lds(
            (const __attribute__((address_space(1))) unsigned int*)esrc,
            (__attribute__((address_space(3))) unsigned int*)((char*)esn_sm + (w << 10)),
            16, 0, 0);
        __builtin_amdgcn_global_load_lds(
            (const __attribute__((address_space(1))) unsigned int*)(esrc + 4096),
            (__attribute__((address_space(3))) unsigned int*)((char*)esn_sm + 4096 + (w << 10)),
            16, 0, 0);
    }
    STAGEP(0, 0);

    // argmax state on s = dot - esq/2  (argmin d2 == argmax s)
    floatx4 mval[RF], mv2[RF], midx[RF];
#pragma unroll
    for (int rf = 0; rf < RF; rf++)
#pragma unroll
        for (int r = 0; r < 4; r++) {
            mval[rf][r] = -3.0e38f; mv2[rf][r] = -3.0e38f; midx[rf][r] = 0.0f;
        }

    float fcol = (float)lrow;                     // maintained: +16 per tile
    __syncthreads();                              // drain prologue stages

    for (int p = 0; p < 64; p += 2) {
        ITER2(0, p);
        ITER2(1, p + 1);                          // last stage wraps; harmless
    }

    float lacc = 0.0f;
#pragma unroll
    for (int rf = 0; rf < RF; rf++)
#pragma unroll
        for (int r = 0; r < 4; r++) {
            float v = mval[rf][r], v2 = mv2[rf][r], fi = midx[rf][r];
            // top-2 max-merge across the 16 lanes of this row (ties: smaller col)
            for (int off = 1; off < 16; off <<= 1) {
                float ov  = __shfl_xor(v,  off, 64);
                float ofi = __shfl_xor(fi, off, 64);
                float ov2 = __shfl_xor(v2, off, 64);
                bool take = (ov > v) || ((ov == v) && (ofi < fi));
                float loser = take ? v : ov;
                v2 = fmaxf(fmaxf(v2, ov2), loser);
                v  = take ? ov  : v;
                fi = take ? ofi : fi;
            }
            int row = row0 + rf * 16 + lq * 4 + r;
            int idx = (int)fi;
            float4 ev = ((const float4*)(const void*)(e + (size_t)idx * ZD))[lrow];
            float4 zv = ((const float4*)(const void*)(z + (size_t)row * ZD))[lrow];
            ((float4*)(void*)(out + (size_t)row * ZD))[lrow] = ev;
            float dx = ev.x - zv.x, dy = ev.y - zv.y;
            float dz = ev.z - zv.z, dw = ev.w - zv.w;
            lacc = fmaf(dx, dx, lacc); lacc = fmaf(dy, dy, lacc);
            lacc = fmaf(dz, dz, lacc); lacc = fmaf(dw, dw, lacc);
            if (lrow == 0) {
                out[(size_t)N_ROWS * ZD + row] = fi;
                if (v - v2 < EPS_S) {
                    unsigned int i = atomicAdd(cntp, 1u);
                    if (i < FLAG_CAP) flags[i] = (unsigned int)row;
                }
            }
        }

    for (int off = 1; off < 64; off <<= 1) lacc += __shfl_xor(lacc, off, 64);
    __shared__ float sm[4];
    if (lane == 0) sm[w] = lacc;
    __syncthreads();
    if (threadIdx.x == 0) atomicAdd(ws, sm[0] + sm[1] + sm[2] + sm[3]);
}

__global__ __launch_bounds__(256) void vq_fixup(
        const float* __restrict__ z, const float* __restrict__ e,
        float* __restrict__ ws, float* __restrict__ out) {
    const double* esq64 = (const double*)((const char*)ws + 16384);
    const float* eT = (const float*)((const char*)ws + 557056);
    const unsigned int* flags = (const unsigned int*)((const char*)ws + 294912);
    unsigned int cnt = ((const unsigned int*)ws)[1];
    // Overflow fallback: if the flag list overflowed, re-solve EVERY row
    // (slow but exact). Expected flags ~10-12K << 65536.
    bool allrows = cnt > FLAG_CAP;
    unsigned int n = allrows ? N_ROWS : cnt;

    // finalize folded in: stream-ordered after vq_mfma, ws[0] is final.
    // (pass-A loss drift from flips ~2e-7 relative -- ignored)
    if (blockIdx.x == 0 && threadIdx.x == 0)
        out[(size_t)N_ROWS * ZD + N_ROWS] = ws[0] * (1.0f / 8388608.0f);

    __shared__ float zrow[ZD];
    __shared__ double sd[4]; __shared__ int si[4]; __shared__ int sbest;
    int t = threadIdx.x, lane = t & 63, w = t >> 6;

    for (unsigned int u = blockIdx.x; u < n; u += gridDim.x) {
        int row = allrows ? (int)u : (int)flags[u];
        __syncthreads();                          // protect zrow from prev iter
        if (t < ZD) zrow[t] = z[(size_t)row * ZD + t];
        __syncthreads();

        double dacc[8];
#pragma unroll
        for (int j = 0; j < 8; j++) dacc[j] = 0.0;
        for (int k = 0; k < ZD; k++) {
            double zk = (double)zrow[k];
            const float* ek = eT + k * KCODES + t;
#pragma unroll
            for (int j = 0; j < 8; j++)
                dacc[j] = fma(zk, (double)ek[256 * j], dacc[j]);
        }
        double dmin = 1.0e300; int imin = 0;
#pragma unroll
        for (int j = 0; j < 8; j++) {             // ascending c: first wins
            int c = t + 256 * j;
            double d = fma(-2.0, dacc[j], esq64[c]);
            if (d < dmin) { dmin = d; imin = c; }
        }
        for (int off = 1; off < 64; off <<= 1) {
            double od = __shfl_xor(dmin, off, 64);
            int    oi = __shfl_xor(imin, off, 64);
            if (od < dmin || (od == dmin && oi < imin)) { dmin = od; imin = oi; }
        }
        if (lane == 0) { sd[w] = dmin; si[w] = imin; }
        __syncthreads();
        if (t == 0) {
            double bd = sd[0]; int bi = si[0];
            for (int q = 1; q < 4; q++)
                if (sd[q] < bd || (sd[q] == bd && si[q] < bi)) { bd = sd[q]; bi = si[q]; }
            sbest = bi;
        }
        __syncthreads();
        int bi = sbest;
        if (t < 16)
            ((float4*)(void*)(out + (size_t)row * ZD))[t] =
                ((const float4*)(const void*)(e + (size_t)bi * ZD))[t];
        if (t == 0) out[(size_t)N_ROWS * ZD + row] = (float)bi;
    }
}

extern "C" void kernel_launch(void* const* d_in, const int* in_sizes, int n_in,
                              void* d_out, int out_size, void* d_ws, size_t ws_size,
                              hipStream_t stream) {
    const float* z = (const float*)d_in[0];
    const float* e = (const float*)d_in[1];
    float* out = (float*)d_out;
    float* ws  = (float*)d_ws;

    prep_kernel<<<dim3(512), dim3(256), 0, stream>>>(e, ws);
    vq_mfma<<<dim3(512), dim3(256), 0, stream>>>(z, e, ws, out);
    vq_fixup<<<dim3(1024), dim3(256), 0, stream>>>(z, e, ws, out);
}

// Round 9
// 182.766 us; speedup vs baseline: 1.1975x; 1.1126x over previous
//
#include <hip/hip_runtime.h>

// VQ quantizer, fp32: z [131072,64], e [2048,64].
// d_out (flat f32): z_q [131072*64] | indices [131072] (floats) | loss [1].
//
// R15 (kept): SINGLE-PRODUCT F16 MFMA scan. 131 -> 96us (MfmaUtil 14.3,
// VALUBusy 47 -- scan is VALU/idle-dominated now). f16 dot error std
// ~1.6e-3 (128 independent RTN roundings, CLT); pairwise ~2.2e-3.
// R16: fixup was the new bottleneck (~45us at ~10K flags): it re-read the
// full 512KB eT PER ROW. Changes:
//  - EPS_S 0.03 -> 0.02 (= 9.1 sigma pairwise; R15 passed at 13 sigma).
//  - vq_fixup batches RFIX=4 rows per eT sweep (dacc[8][4] f64, 64 VGPR;
//    4 z-rows in LDS): eT traffic /4, epilogue reduced to 2 barriers via
//    parallel 4-row reduce/write.
// Scan kernel byte-identical to R15. Flags CAP 65536 + scan-all fallback.

#define N_ROWS 131072
#define ZD 64
#define KCODES 2048
#define RF 4                 // 16-row fragments per wave (64 rows/wave)
#define EPS_S 0.02f          // 9.1 sigma of f16 scan pairwise error
#define FLAG_CAP 65536
#define RFIX 4               // rows per eT sweep in fixup

using f16x8   = __attribute__((ext_vector_type(8))) _Float16;
using floatx4 = __attribute__((ext_vector_type(4))) float;

// ws byte layout:
//       0: loss f32 | 4: flag count u32
//    4096: esn f32[2048]   (= -esq/2, summed in f64)
//   16384: esq64 f64[2048]
//   32768: et16, 128 tiles x 2048B; tile = [kb 0..7][code 0..15][8 k] f16
//          (kb = dim>>3, j = dim&7)   ends 294912
//  294912: flags u32[65536]   (ends 557056)
//  557056: eT f32[64*2048]    (ends 1081344)

__global__ void prep_kernel(const float* __restrict__ e, float* __restrict__ ws) {
    int t = threadIdx.x, lane = t & 63, w = t >> 6;
    if (blockIdx.x == 0 && t == 0) { ws[0] = 0.0f; ((unsigned int*)ws)[1] = 0u; }
    int c = blockIdx.x * 4 + w;                   // 512 blocks x 4 waves = 2048
    float* esn = ws + 1024;
    double* esq64 = (double*)((char*)ws + 16384);
    unsigned short* et = (unsigned short*)((char*)ws + 32768);
    float* eT = (float*)((char*)ws + 557056);

    float x = e[(size_t)c * ZD + lane];           // lane = dim k, coalesced
    union { _Float16 h; unsigned short u; } cv;
    cv.h = (_Float16)x;                           // RTN f32->f16
    // swizzled tile layout: tile = c>>4, 1024 u16 per tile
    int base = ((c >> 4) << 10) + ((lane >> 3) << 7) + ((c & 15) << 3) + (lane & 7);
    et[base] = cv.u;
    eT[lane * KCODES + c] = x;
    double s = (double)x * (double)x;
    for (int off = 1; off < 64; off <<= 1) s += __shfl_xor(s, off, 64);
    if (lane == 0) { esq64[c] = s; esn[c] = (float)(-0.5 * s); }
}

// 8 MFMAs + argmax update for one 16-code tile (single f16 product).
// Top-2 invariant mval >= mv2: new mv2 = median(s, mval_old, mv2).
#define COMPUTE(H0, H1, EN, FCOL) do {                                       \
    floatx4 _ai = {EN, EN, EN, EN};                                          \
    _Pragma("unroll")                                                        \
    for (int _rf = 0; _rf < RF; _rf++) {                                     \
        floatx4 acc;                                                         \
        acc = __builtin_amdgcn_mfma_f32_16x16x32_f16(Fh[_rf][0], H0, _ai, 0, 0, 0); \
        acc = __builtin_amdgcn_mfma_f32_16x16x32_f16(Fh[_rf][1], H1, acc, 0, 0, 0); \
        _Pragma("unroll")                                                    \
        for (int _r = 0; _r < 4; _r++) {                                     \
            float _s  = acc[_r];                                             \
            bool  _gt = _s > mval[_rf][_r];                                  \
            mv2[_rf][_r]  = __builtin_amdgcn_fmed3f(_s, mval[_rf][_r], mv2[_rf][_r]); \
            midx[_rf][_r] = _gt ? (FCOL) : midx[_rf][_r];                    \
            mval[_rf][_r] = fmaxf(_s, mval[_rf][_r]);                        \
        }                                                                    \
    }                                                                        \
} while (0)

// Stage one 4KB PAIR of tiles (2x 2KB) into slab BUF: 256 thr x 16B, linear.
#define STAGEP(BUF, P) do {                                                  \
    const char* _src = etiles + ((size_t)((P) & 63) << 12)                   \
                       + ((size_t)threadIdx.x << 4);                         \
    __builtin_amdgcn_global_load_lds(                                        \
        (const __attribute__((address_space(1))) unsigned int*)_src,         \
        (__attribute__((address_space(3))) unsigned int*)&tilebuf[BUF][w << 10], \
        16, 0, 0);                                                           \
} while (0)

// One pipeline step over a tile PAIR: stage pair P+1, compute tiles 2P,2P+1.
#define ITER2(BUF, P) do {                                                   \
    STAGEP((BUF) ^ 1, (P) + 1);                                              \
    float _en0 = esn_sm[(P) * 32 + lrow];                                    \
    float _en1 = esn_sm[(P) * 32 + 16 + lrow];                               \
    f16x8 h0, h1;                                                            \
    h0 = *(const f16x8*)(const void*)(tilebuf[BUF] + (lane << 4));           \
    h1 = *(const f16x8*)(const void*)(tilebuf[BUF] + 1024 + (lane << 4));    \
    COMPUTE(h0, h1, _en0, fcol);                                             \
    fcol += 16.0f;                                                           \
    h0 = *(const f16x8*)(const void*)(tilebuf[BUF] + 2048 + (lane << 4));    \
    h1 = *(const f16x8*)(const void*)(tilebuf[BUF] + 3072 + (lane << 4));    \
    COMPUTE(h0, h1, _en1, fcol);                                             \
    fcol += 16.0f;                                                           \
    __syncthreads();                                                         \
} while (0)

__global__ __launch_bounds__(256, 2) void vq_mfma(
        const float* __restrict__ z, const float* __restrict__ e,
        float* __restrict__ ws, float* __restrict__ out) {
    const char* etiles = (const char*)ws + 32768;
    unsigned int* cntp  = (unsigned int*)ws + 1;
    unsigned int* flags = (unsigned int*)((char*)ws + 294912);

    __shared__ __attribute__((aligned(16))) char tilebuf[2][4096];
    __shared__ __attribute__((aligned(16))) float esn_sm[KCODES];

    int lane = threadIdx.x & 63;
    int w    = threadIdx.x >> 6;
    int wid  = blockIdx.x * 4 + w;                // 0..2047
    int row0 = wid * (RF * 16);                   // 64 rows per wave
    int lrow = lane & 15;
    int lq   = lane >> 4;

    // Resident A fragments (f16), A[m=lane&15][k=lq*8+j], kc = k-half
    f16x8 Fh[RF][2];
#pragma unroll
    for (int rf = 0; rf < RF; rf++)
#pragma unroll
        for (int kc = 0; kc < 2; kc++) {
            const float* zp = z + (size_t)(row0 + rf * 16 + lrow) * ZD + kc * 32 + lq * 8;
            float xv[8];
            *(float4*)(void*)&xv[0] = *(const float4*)(const void*)zp;
            *(float4*)(void*)&xv[4] = *(const float4*)(const void*)(zp + 4);
            f16x8 h;
#pragma unroll
            for (int j = 0; j < 8; j++) h[j] = (_Float16)xv[j];
            Fh[rf][kc] = h;
            // Pin (ONE-TIME, outside loop): asm defs cannot be rematerialized
            // -> fragments stay register-resident across the loop.
            asm volatile("" : "+v"(Fh[rf][kc]));
        }

    // Prologue staging: esn (8KB, 2 calls) + pair 0.
    {
        const char* esrc = (const char*)ws + 4096 + ((size_t)threadIdx.x << 4);
        __builtin_amdgcn_global_load_lds(
            (const __attribute__((address_space(1))) unsigned int*)esrc,
            (__attribute__((address_space(3))) unsigned int*)((char*)esn_sm + (w << 10)),
            16, 0, 0);
        __builtin_amdgcn_global_load_lds(
            (const __attribute__((address_space(1))) unsigned int*)(esrc + 4096),
            (__attribute__((address_space(3))) unsigned int*)((char*)esn_sm + 4096 + (w << 10)),
            16, 0, 0);
    }
    STAGEP(0, 0);

    // argmax state on s = dot - esq/2  (argmin d2 == argmax s)
    floatx4 mval[RF], mv2[RF], midx[RF];
#pragma unroll
    for (int rf = 0; rf < RF; rf++)
#pragma unroll
        for (int r = 0; r < 4; r++) {
            mval[rf][r] = -3.0e38f; mv2[rf][r] = -3.0e38f; midx[rf][r] = 0.0f;
        }

    float fcol = (float)lrow;                     // maintained: +16 per tile
    __syncthreads();                              // drain prologue stages

    for (int p = 0; p < 64; p += 2) {
        ITER2(0, p);
        ITER2(1, p + 1);                          // last stage wraps; harmless
    }

    float lacc = 0.0f;
#pragma unroll
    for (int rf = 0; rf < RF; rf++)
#pragma unroll
        for (int r = 0; r < 4; r++) {
            float v = mval[rf][r], v2 = mv2[rf][r], fi = midx[rf][r];
            // top-2 max-merge across the 16 lanes of this row (ties: smaller col)
            for (int off = 1; off < 16; off <<= 1) {
                float ov  = __shfl_xor(v,  off, 64);
                float ofi = __shfl_xor(fi, off, 64);
                float ov2 = __shfl_xor(v2, off, 64);
                bool take = (ov > v) || ((ov == v) && (ofi < fi));
                float loser = take ? v : ov;
                v2 = fmaxf(fmaxf(v2, ov2), loser);
                v  = take ? ov  : v;
                fi = take ? ofi : fi;
            }
            int row = row0 + rf * 16 + lq * 4 + r;
            int idx = (int)fi;
            float4 ev = ((const float4*)(const void*)(e + (size_t)idx * ZD))[lrow];
            float4 zv = ((const float4*)(const void*)(z + (size_t)row * ZD))[lrow];
            ((float4*)(void*)(out + (size_t)row * ZD))[lrow] = ev;
            float dx = ev.x - zv.x, dy = ev.y - zv.y;
            float dz = ev.z - zv.z, dw = ev.w - zv.w;
            lacc = fmaf(dx, dx, lacc); lacc = fmaf(dy, dy, lacc);
            lacc = fmaf(dz, dz, lacc); lacc = fmaf(dw, dw, lacc);
            if (lrow == 0) {
                out[(size_t)N_ROWS * ZD + row] = fi;
                if (v - v2 < EPS_S) {
                    unsigned int i = atomicAdd(cntp, 1u);
                    if (i < FLAG_CAP) flags[i] = (unsigned int)row;
                }
            }
        }

    for (int off = 1; off < 64; off <<= 1) lacc += __shfl_xor(lacc, off, 64);
    __shared__ float sm[4];
    if (lane == 0) sm[w] = lacc;
    __syncthreads();
    if (threadIdx.x == 0) atomicAdd(ws, sm[0] + sm[1] + sm[2] + sm[3]);
}

// Exact f64 re-solve, RFIX rows per eT sweep (eT traffic / RFIX).
__global__ __launch_bounds__(256) void vq_fixup(
        const float* __restrict__ z, const float* __restrict__ e,
        float* __restrict__ ws, float* __restrict__ out) {
    const double* esq64 = (const double*)((const char*)ws + 16384);
    const float* eT = (const float*)((const char*)ws + 557056);
    const unsigned int* flags = (const unsigned int*)((const char*)ws + 294912);
    unsigned int cnt = ((const unsigned int*)ws)[1];
    // Overflow fallback: if the flag list overflowed, re-solve EVERY row.
    bool allrows = cnt > FLAG_CAP;
    unsigned int n = allrows ? N_ROWS : cnt;

    // finalize folded in: stream-ordered after vq_mfma, ws[0] is final.
    // (pass-A loss drift from flips <= 2*EPS*flags/8.4M ~ 3e-5 -- ignored)
    if (blockIdx.x == 0 && threadIdx.x == 0)
        out[(size_t)N_ROWS * ZD + N_ROWS] = ws[0] * (1.0f / 8388608.0f);
    if (n == 0) return;

    __shared__ float zrow[RFIX][ZD];
    __shared__ int rows_sm[RFIX];
    __shared__ double sd[4][RFIX]; __shared__ int si[4][RFIX];
    __shared__ int sbest[RFIX];
    int t = threadIdx.x, lane = t & 63, w = t >> 6;

    unsigned int ngroups = (n + RFIX - 1) / RFIX;
    for (unsigned int g = blockIdx.x; g < ngroups; g += gridDim.x) {
        __syncthreads();                          // protect LDS from prev iter
        if (t < RFIX) {
            unsigned int u = g * RFIX + (unsigned int)t;
            if (u >= n) u = n - 1;                // pad: duplicate last row
            rows_sm[t] = allrows ? (int)u : (int)flags[u];
        }
        __syncthreads();
        // stage RFIX z rows: 256 threads cover 4 rows x 64 dims
        zrow[t >> 6][t & 63] = z[(size_t)rows_sm[t >> 6] * ZD + (t & 63)];
        __syncthreads();

        double dacc[8][RFIX];
#pragma unroll
        for (int j = 0; j < 8; j++)
#pragma unroll
            for (int r = 0; r < RFIX; r++) dacc[j][r] = 0.0;

        for (int k = 0; k < ZD; k++) {
            const float* ek = eT + k * KCODES + t;
            float e8[8];
#pragma unroll
            for (int j = 0; j < 8; j++) e8[j] = ek[256 * j];
#pragma unroll
            for (int r = 0; r < RFIX; r++) {
                double zk = (double)zrow[r][k];
#pragma unroll
                for (int j = 0; j < 8; j++)
                    dacc[j][r] = fma(zk, (double)e8[j], dacc[j][r]);
            }
        }

        // per-row argmin: thread-local over 8 codes, wave shfl, block merge
#pragma unroll
        for (int r = 0; r < RFIX; r++) {
            double dmin = 1.0e300; int imin = 0;
#pragma unroll
            for (int j = 0; j < 8; j++) {         // ascending c: first wins
                int c = t + 256 * j;
                double d = fma(-2.0, dacc[j][r], esq64[c]);
                if (d < dmin) { dmin = d; imin = c; }
            }
            for (int off = 1; off < 64; off <<= 1) {
                double od = __shfl_xor(dmin, off, 64);
                int    oi = __shfl_xor(imin, off, 64);
                if (od < dmin || (od == dmin && oi < imin)) { dmin = od; imin = oi; }
            }
            if (lane == 0) { sd[w][r] = dmin; si[w][r] = imin; }
        }
        __syncthreads();
        if (t < RFIX) {
            double bd = sd[0][t]; int bi = si[0][t];
            for (int q = 1; q < 4; q++)
                if (sd[q][t] < bd || (sd[q][t] == bd && si[q][t] < bi)) {
                    bd = sd[q][t]; bi = si[q][t];
                }
            sbest[t] = bi;
        }
        __syncthreads();
        // parallel write: t<64 -> row r=t>>4, float4 slot pos=t&15
        if (t < 16 * RFIX) {
            int r = t >> 4, pos = t & 15;
            unsigned int u = g * RFIX + (unsigned int)r;
            if (u < n) {                          // skip padded duplicates
                int row = rows_sm[r]; int bi = sbest[r];
                ((float4*)(void*)(out + (size_t)row * ZD))[pos] =
                    ((const float4*)(const void*)(e + (size_t)bi * ZD))[pos];
                if (pos == 0) out[(size_t)N_ROWS * ZD + row] = (float)bi;
            }
        }
    }
}

extern "C" void kernel_launch(void* const* d_in, const int* in_sizes, int n_in,
                              void* d_out, int out_size, void* d_ws, size_t ws_size,
                              hipStream_t stream) {
    const float* z = (const float*)d_in[0];
    const float* e = (const float*)d_in[1];
    float* out = (float*)d_out;
    float* ws  = (float*)d_ws;

    prep_kernel<<<dim3(512), dim3(256), 0, stream>>>(e, ws);
    vq_mfma<<<dim3(512), dim3(256), 0, stream>>>(z, e, ws, out);
    vq_fixup<<<dim3(1024), dim3(256), 0, stream>>>(z, e, ws, out);
}